// Round 6
// baseline (356.090 us; speedup 1.0000x reference)
//
#include <hip/hip_runtime.h>

#define NEGF -1e30f
typedef unsigned int uint32;

static constexpr int Bb = 64, Tt = 2048, Vv = 256, Uu = 256;
// S = 2*U+1 = 513 states; lane l owns states 8l..8l+7 (+512 on lane 63).
// Ebs layout (per batch, 2048 floats): Ebs[i] = blank[i+1] for i=0..2046,
// Ebs[2047] = blank[0].

__device__ __forceinline__ unsigned short f2bf(float f) {    // RNE, no NaN inputs
  uint32 u = __builtin_bit_cast(uint32, f);
  u += 0x7fffu + ((u >> 16) & 1u);
  return (unsigned short)(u >> 16);
}
__device__ __forceinline__ float bf2f_lo(uint32 p) { return __builtin_bit_cast(float, p << 16); }
__device__ __forceinline__ float bf2f_hi(uint32 p) { return __builtin_bit_cast(float, p & 0xffff0000u); }

// ---------------------------------------------------------------------------
// Kernel A: one streaming pass over logits; 8 rows in flight per wave.
// ---------------------------------------------------------------------------
__global__ __launch_bounds__(256) void gather_lse_kernel(
    const float* __restrict__ logits, const int* __restrict__ targets,
    const int* __restrict__ llen, float* __restrict__ acc,
    float* __restrict__ Ebs, unsigned short* __restrict__ E) {
  __shared__ __align__(16) float buf[4][8][Vv];   // 32 KB
  __shared__ float wpart[4];
  const int b = blockIdx.x >> 5;
  const int c = blockIdx.x & 31;
  const int w = threadIdx.x >> 6;
  const int lane = threadIdx.x & 63;
  const int L = llen[b];
  const int4 lb = reinterpret_cast<const int4*>(targets + (b << 8))[lane];
  const float* __restrict__ lgb = logits + (size_t)b * (Tt * Vv);
  float lse_local = 0.f;
#pragma unroll
  for (int k = 0; k < 2; ++k) {
    const int tbase = (c << 6) + (k << 5) + w;    // rows tbase + 4j, j=0..7
    if (tbase >= L) break;                        // wave-uniform
    float4 v[8];
#pragma unroll
    for (int j = 0; j < 8; ++j)
      v[j] = reinterpret_cast<const float4*>(lgb + (size_t)(tbase + 4 * j) * Vv)[lane];
    float s[8];
#pragma unroll
    for (int j = 0; j < 8; ++j)
      s[j] = __expf(v[j].x) + __expf(v[j].y) + __expf(v[j].z) + __expf(v[j].w);
#pragma unroll
    for (int off = 32; off; off >>= 1) {
#pragma unroll
      for (int j = 0; j < 8; ++j) s[j] += __shfl_down(s[j], off);
    }
#pragma unroll
    for (int j = 0; j < 8; ++j)
      reinterpret_cast<float4*>(&buf[w][j][0])[lane] = v[j];
#pragma unroll
    for (int j = 0; j < 8; ++j) {                 // intra-wave DS ordering
      const int t = tbase + 4 * j;
      const bool val = t < L;
      ushort4 o;
      o.x = f2bf(buf[w][j][lb.x]); o.y = f2bf(buf[w][j][lb.y]);
      o.z = f2bf(buf[w][j][lb.z]); o.w = f2bf(buf[w][j][lb.w]);
      if (val)
        reinterpret_cast<ushort4*>(E + ((size_t)((b << 11) + t)) * Vv)[lane] = o;
      if ((lane == 0) & val) {
        lse_local += __logf(s[j]);
        Ebs[(b << 11) + ((t == 0) ? 2047 : t - 1)] = v[j].x;   // row[0] = blank
      }
    }
  }
  if (lane == 0) wpart[w] = lse_local;
  __syncthreads();
  if (threadIdx.x == 0)
    atomicAdd(acc, wpart[0] + wpart[1] + wpart[2] + wpart[3]);
}

// ---------------------------------------------------------------------------
// Kernel B: bidirectional Viterbi, 2 waves/batch, register ring + HALO scheme.
// No per-step cross-lane ops: each lane mirrors its neighbor's 8 states in
// registers (triangular catch-up updates, bit-identical arithmetic), re-synced
// once per 4-step group via an LDS exchange. Neighbor emissions come from a
// duplicated global load in the same deep prefetch ring.
// ---------------------------------------------------------------------------
#define PG 6
__global__ __launch_bounds__(128) void viterbi_kernel(
    const unsigned short* __restrict__ E, const float* __restrict__ Ebs,
    const int* __restrict__ targets, const int* __restrict__ llen,
    const int* __restrict__ tlen, float* __restrict__ acc) {
  __shared__ __align__(16) float LB[2048];   // blanks (shifted layout), 8 KB
  __shared__ float Bt[520];
  __shared__ __align__(16) float4 Hf[130];   // forward halo exchange: 65 slots
  __shared__ __align__(16) float4 Hb[130];   // backward halo exchange
  const int b = blockIdx.x;
  const int lane = threadIdx.x & 63;
  const int wv = threadIdx.x >> 6;
  const int L = llen[b];
  const int tl = tlen[b];
  const int M = (L - 2) >> 1;
  const int4 lb = reinterpret_cast<const int4*>(targets + (b << 8))[lane];
  const uint2* __restrict__ Erow = reinterpret_cast<const uint2*>(E) + ((size_t)(b << 11) << 6);
  const float* __restrict__ Ebb = Ebs + (b << 11);

  // cooperative blank preload: 2048 floats
  {
    const float4* src = reinterpret_cast<const float4*>(Ebb);
    float4* dst = reinterpret_cast<float4*>(LB);
    for (int i = threadIdx.x; i < 512; i += 128) dst[i] = src[i];
  }
  __syncthreads();

  float a0 = NEGF, a1 = NEGF, a2 = NEGF, a3 = NEGF, a4 = NEGF,
        a5 = NEGF, a6 = NEGF, a7 = NEGF, a8 = NEGF;
  float h0 = NEGF, h1 = NEGF, h2 = NEGF, h3 = NEGF,
        h4 = NEGF, h5 = NEGF, h6 = NEGF, h7 = NEGF;

  if (wv == 0) {
    // ================= forward wave =================
    const int prevw = __shfl_up(lb.w, 1);
    const bool sk0 = (lane != 0) && (lb.x != prevw);
    const bool sk1 = (lb.y != lb.x);
    const bool sk2 = (lb.z != lb.y);
    const bool sk3 = (lb.w != lb.z);
    const bool bh1 = __shfl_up((int)sk1, 1) != 0;   // neighbor's sk1..sk3
    const bool bh2 = __shfl_up((int)sk2, 1) != 0;
    const bool bh3 = __shfl_up((int)sk3, 1) != 0;
    if (lane == 0) {
      a0 = LB[2047];                                            // blank[0]
      a1 = bf2f_lo((uint32)*reinterpret_cast<const unsigned short*>(E + ((size_t)(b << 11) << 8)));
      Hf[0] = make_float4(NEGF, NEGF, NEGF, NEGF);              // slot 0 = no neighbor
      Hf[1] = make_float4(NEGF, NEGF, NEGF, NEGF);
    }
    uint2 po[PG][4], pn[PG][4];
    float4 pb[PG];
    auto fetchf = [&](int slot, int k) {
      const int kk = (k > 511) ? 511 : k;
#pragma unroll
      for (int j = 0; j < 4; ++j) {
        int r = 1 + 4 * kk + j; r = (r > 2047) ? 2047 : r;
        po[slot][j] = Erow[(size_t)(r << 6) + lane];
        pn[slot][j] = reinterpret_cast<const uint2*>(
            (const char*)Erow + ((size_t)(r << 6) + lane) * 8 - 8)[0];  // lane-1
      }
      pb[slot] = reinterpret_cast<const float4*>(LB)[kk];       // blank[4kk+1..4kk+4]
    };
    auto refreshf = [&]() {
      Hf[2 * lane + 2] = make_float4(a0, a1, a2, a3);
      Hf[2 * lane + 3] = make_float4(a4, a5, a6, a7);
      const float4 v0 = Hf[2 * lane];
      const float4 v1 = Hf[2 * lane + 1];
      h0 = v0.x; h1 = v0.y; h2 = v0.z; h3 = v0.w;
      h4 = v1.x; h5 = v1.y; h6 = v1.z; h7 = v1.w;
    };
    auto stepf = [&](uint2 em, float eb) {        // am1 == h7 (current level)
      const float e0 = bf2f_lo(em.x), e1 = bf2f_hi(em.x);
      const float e2 = bf2f_lo(em.y), e3 = bf2f_hi(em.y);
      const float am1 = h7;
      const float x0 = fmaxf(a0, am1) + eb;
      const float x1 = fmaxf(fmaxf(a1, a0), sk0 ? am1 : NEGF) + e0;
      const float x2 = fmaxf(a2, a1) + eb;
      const float x3 = fmaxf(fmaxf(a3, a2), sk1 ? a1 : NEGF) + e1;
      const float x4 = fmaxf(a4, a3) + eb;
      const float x5 = fmaxf(fmaxf(a5, a4), sk2 ? a3 : NEGF) + e2;
      const float x6 = fmaxf(a6, a5) + eb;
      const float x7 = fmaxf(fmaxf(a7, a6), sk3 ? a5 : NEGF) + e3;
      const float x8 = fmaxf(a8, a7) + eb;
      a0 = x0; a1 = x1; a2 = x2; a3 = x3; a4 = x4; a5 = x5; a6 = x6; a7 = x7; a8 = x8;
    };
    auto catch1 = [&](uint2 nem, float eb) {      // update h3..h7
      const float ne1 = bf2f_hi(nem.x), ne2 = bf2f_lo(nem.y), ne3 = bf2f_hi(nem.y);
      const float t3 = fmaxf(fmaxf(h3, h2), bh1 ? h1 : NEGF) + ne1;
      const float t4 = fmaxf(h4, h3) + eb;
      const float t5 = fmaxf(fmaxf(h5, h4), bh2 ? h3 : NEGF) + ne2;
      const float t6 = fmaxf(h6, h5) + eb;
      const float t7 = fmaxf(fmaxf(h7, h6), bh3 ? h5 : NEGF) + ne3;
      h3 = t3; h4 = t4; h5 = t5; h6 = t6; h7 = t7;
    };
    auto catch2 = [&](uint2 nem, float eb) {      // update h5..h7
      const float ne2 = bf2f_lo(nem.y), ne3 = bf2f_hi(nem.y);
      const float t5 = fmaxf(fmaxf(h5, h4), bh2 ? h3 : NEGF) + ne2;
      const float t6 = fmaxf(h6, h5) + eb;
      const float t7 = fmaxf(fmaxf(h7, h6), bh3 ? h5 : NEGF) + ne3;
      h5 = t5; h6 = t6; h7 = t7;
    };
    auto catch3 = [&](uint2 nem) {                // update h7
      const float ne3 = bf2f_hi(nem.y);
      h7 = fmaxf(fmaxf(h7, h6), bh3 ? h5 : NEGF) + ne3;
    };
    auto do_group = [&](int s) {
      stepf(po[s][0], pb[s].x);  catch1(pn[s][0], pb[s].x);
      stepf(po[s][1], pb[s].y);  catch2(pn[s][1], pb[s].y);
      stepf(po[s][2], pb[s].z);  catch3(pn[s][2]);
      stepf(po[s][3], pb[s].w);  refreshf();
    };
    const int n = M, G = n >> 2, rem = n & 3;
    refreshf();                                   // initial halo
#pragma unroll
    for (int s = 0; s < PG; ++s) fetchf(s, s);
    __builtin_amdgcn_sched_barrier(0);
    int g = 0;
    while (g + PG <= G) {
#pragma unroll
      for (int s = 0; s < PG; ++s) {
        do_group(s);
        fetchf(s, g + s + PG);
        __builtin_amdgcn_sched_barrier(0);
      }
      g += PG;
    }
    const int left = G - g;                       // 0..PG-1, full groups
#pragma unroll
    for (int s = 0; s < PG; ++s)
      if (s < left) do_group(s);
    for (int i = 0; i < rem; ++i) {               // tail: shfl-based steps
      const int r = 1 + 4 * G + i;
      const uint2 em = Erow[(size_t)(r << 6) + lane];
      const float eb = LB[r - 1];
      const float e0 = bf2f_lo(em.x), e1 = bf2f_hi(em.x);
      const float e2 = bf2f_lo(em.y), e3 = bf2f_hi(em.y);
      float am1 = __shfl_up(a7, 1);
      if (lane == 0) am1 = NEGF;
      const float x0 = fmaxf(a0, am1) + eb;
      const float x1 = fmaxf(fmaxf(a1, a0), sk0 ? am1 : NEGF) + e0;
      const float x2 = fmaxf(a2, a1) + eb;
      const float x3 = fmaxf(fmaxf(a3, a2), sk1 ? a1 : NEGF) + e1;
      const float x4 = fmaxf(a4, a3) + eb;
      const float x5 = fmaxf(fmaxf(a5, a4), sk2 ? a3 : NEGF) + e2;
      const float x6 = fmaxf(a6, a5) + eb;
      const float x7 = fmaxf(fmaxf(a7, a6), sk3 ? a5 : NEGF) + e3;
      const float x8 = fmaxf(a8, a7) + eb;
      a0 = x0; a1 = x1; a2 = x2; a3 = x3; a4 = x4; a5 = x5; a6 = x6; a7 = x7; a8 = x8;
    }
  } else {
    // ================= backward wave =================
    const int nlabx = __shfl_down(lb.x, 1);
    const bool kb0 = (lb.y != lb.x);
    const bool kb1 = (lb.z != lb.y);
    const bool kb2 = (lb.w != lb.z);
    const bool kb3 = (lane < 63) && (nlabx != lb.w);
    const bool gh0 = __shfl_down((int)kb0, 1) != 0;   // neighbor's kb0..kb2
    const bool gh1 = __shfl_down((int)kb1, 1) != 0;
    const bool gh2 = __shfl_down((int)kb2, 1) != 0;
    {
      const uint2 er = Erow[(size_t)((L - 1) << 6) + lane];
      const float e0 = bf2f_lo(er.x), e1 = bf2f_hi(er.x);
      const float e2 = bf2f_lo(er.y), e3 = bf2f_hi(er.y);
      const float blankL = LB[L - 2];                           // blank[L-1]
      const int s0 = 8 * lane, tb = 2 * tl, tm = 2 * tl - 1;
      a0 = (s0     == tb) ? blankL : NEGF;
      a1 = (s0 + 1 == tm) ? e0     : NEGF;
      a2 = (s0 + 2 == tb) ? blankL : NEGF;
      a3 = (s0 + 3 == tm) ? e1     : NEGF;
      a4 = (s0 + 4 == tb) ? blankL : NEGF;
      a5 = (s0 + 5 == tm) ? e2     : NEGF;
      a6 = (s0 + 6 == tb) ? blankL : NEGF;
      a7 = (s0 + 7 == tm) ? e3     : NEGF;
      a8 = ((lane == 63) && (tb == 512)) ? blankL : NEGF;
      if (lane == 63) Hb[129] = make_float4(NEGF, NEGF, NEGF, NEGF);
    }
    uint2 po[PG][4], pn[PG][4];
    float pq[PG][4];
    auto fetchb = [&](int slot, int k) {
#pragma unroll
      for (int j = 0; j < 4; ++j) {
        int r = L - 2 - 4 * k - j; r = (r < 1) ? 1 : r;
        po[slot][j] = Erow[(size_t)(r << 6) + lane];
        pn[slot][j] = reinterpret_cast<const uint2*>(
            (const char*)Erow + ((size_t)(r << 6) + lane) * 8 + 8)[0];  // lane+1
        pq[slot][j] = LB[r - 1];                                // blank[r]
      }
    };
    auto refreshb = [&]() {
      Hb[2 * lane]     = make_float4(a0, a1, a2, a3);
      Hb[2 * lane + 1] = make_float4(a4, a5, a6, a7);
      if (lane == 63) Hb[128] = make_float4(a8, NEGF, NEGF, NEGF);
      const float4 v0 = Hb[2 * lane + 2];
      const float4 v1 = Hb[2 * lane + 3];
      h0 = v0.x; h1 = v0.y; h2 = v0.z; h3 = v0.w;
      h4 = v1.x; h5 = v1.y; h6 = v1.z; h7 = v1.w;
    };
    auto stepb = [&](uint2 em, float eb) {        // bn0 == h0, bn1 == h1
      const float e0 = bf2f_lo(em.x), e1 = bf2f_hi(em.x);
      const float e2 = bf2f_lo(em.y), e3 = bf2f_hi(em.y);
      const float y0 = fmaxf(a0, a1) + eb;
      const float y1 = fmaxf(fmaxf(a1, a2), kb0 ? a3 : NEGF) + e0;
      const float y2 = fmaxf(a2, a3) + eb;
      const float y3 = fmaxf(fmaxf(a3, a4), kb1 ? a5 : NEGF) + e1;
      const float y4 = fmaxf(a4, a5) + eb;
      const float y5 = fmaxf(fmaxf(a5, a6), kb2 ? a7 : NEGF) + e2;
      const float y6 = fmaxf(a6, a7) + eb;
      const float y7 = fmaxf(fmaxf(a7, h0), kb3 ? h1 : NEGF) + e3;
      const float y8 = a8 + eb;
      a0 = y0; a1 = y1; a2 = y2; a3 = y3; a4 = y4; a5 = y5; a6 = y6; a7 = y7; a8 = y8;
    };
    auto catch1 = [&](uint2 nem, float eb) {      // update h0..h5
      const float ne0 = bf2f_lo(nem.x), ne1 = bf2f_hi(nem.x), ne2 = bf2f_lo(nem.y);
      const float t0 = fmaxf(h0, h1) + eb;
      const float t1 = fmaxf(fmaxf(h1, h2), gh0 ? h3 : NEGF) + ne0;
      const float t2 = fmaxf(h2, h3) + eb;
      const float t3 = fmaxf(fmaxf(h3, h4), gh1 ? h5 : NEGF) + ne1;
      const float t4 = fmaxf(h4, h5) + eb;
      const float t5 = fmaxf(fmaxf(h5, h6), gh2 ? h7 : NEGF) + ne2;
      h0 = t0; h1 = t1; h2 = t2; h3 = t3; h4 = t4; h5 = t5;
    };
    auto catch2 = [&](uint2 nem, float eb) {      // update h0..h3
      const float ne0 = bf2f_lo(nem.x), ne1 = bf2f_hi(nem.x);
      const float t0 = fmaxf(h0, h1) + eb;
      const float t1 = fmaxf(fmaxf(h1, h2), gh0 ? h3 : NEGF) + ne0;
      const float t2 = fmaxf(h2, h3) + eb;
      const float t3 = fmaxf(fmaxf(h3, h4), gh1 ? h5 : NEGF) + ne1;
      h0 = t0; h1 = t1; h2 = t2; h3 = t3;
    };
    auto catch3 = [&](uint2 nem, float eb) {      // update h0..h1
      const float ne0 = bf2f_lo(nem.x);
      const float t0 = fmaxf(h0, h1) + eb;
      const float t1 = fmaxf(fmaxf(h1, h2), gh0 ? h3 : NEGF) + ne0;
      h0 = t0; h1 = t1;
    };
    auto do_group = [&](int s) {
      stepb(po[s][0], pq[s][0]);  catch1(pn[s][0], pq[s][0]);
      stepb(po[s][1], pq[s][1]);  catch2(pn[s][1], pq[s][1]);
      stepb(po[s][2], pq[s][2]);  catch3(pn[s][2], pq[s][2]);
      stepb(po[s][3], pq[s][3]);  refreshb();
    };
    const int n = L - 2 - M, G = n >> 2, rem = n & 3;
    refreshb();                                   // initial halo
#pragma unroll
    for (int s = 0; s < PG; ++s) fetchb(s, s);
    __builtin_amdgcn_sched_barrier(0);
    int g = 0;
    while (g + PG <= G) {
#pragma unroll
      for (int s = 0; s < PG; ++s) {
        do_group(s);
        fetchb(s, g + s + PG);
        __builtin_amdgcn_sched_barrier(0);
      }
      g += PG;
    }
    const int left = G - g;
#pragma unroll
    for (int s = 0; s < PG; ++s)
      if (s < left) do_group(s);
    for (int i = 0; i < rem; ++i) {               // tail: shfl-based steps
      const int r = L - 2 - 4 * G - i;
      const uint2 em = Erow[(size_t)(r << 6) + lane];
      const float eb = LB[r - 1];
      const float e0 = bf2f_lo(em.x), e1 = bf2f_hi(em.x);
      const float e2 = bf2f_lo(em.y), e3 = bf2f_hi(em.y);
      float bn0 = __shfl_down(a0, 1);
      float bn1 = __shfl_down(a1, 1);
      bn0 = (lane == 63) ? a8 : bn0;
      const float y0 = fmaxf(a0, a1) + eb;
      const float y1 = fmaxf(fmaxf(a1, a2), kb0 ? a3 : NEGF) + e0;
      const float y2 = fmaxf(a2, a3) + eb;
      const float y3 = fmaxf(fmaxf(a3, a4), kb1 ? a5 : NEGF) + e1;
      const float y4 = fmaxf(a4, a5) + eb;
      const float y5 = fmaxf(fmaxf(a5, a6), kb2 ? a7 : NEGF) + e2;
      const float y6 = fmaxf(a6, a7) + eb;
      const float y7 = fmaxf(fmaxf(a7, bn0), kb3 ? bn1 : NEGF) + e3;
      const float y8 = a8 + eb;
      a0 = y0; a1 = y1; a2 = y2; a3 = y3; a4 = y4; a5 = y5; a6 = y6; a7 = y7; a8 = y8;
    }
    // dump beta[M+1] to LDS (+NEG padding)
    Bt[8 * lane + 0] = a0; Bt[8 * lane + 1] = a1;
    Bt[8 * lane + 2] = a2; Bt[8 * lane + 3] = a3;
    Bt[8 * lane + 4] = a4; Bt[8 * lane + 5] = a5;
    Bt[8 * lane + 6] = a6; Bt[8 * lane + 7] = a7;
    if (lane == 63) Bt[512] = a8;
    if (lane == 0) { Bt[513] = NEGF; Bt[514] = NEGF; }
  }
  __syncthreads();
  if (wv == 0) {
    const int nlabx = __shfl_down(lb.x, 1);
    const bool kb0 = (lb.y != lb.x);
    const bool kb1 = (lb.z != lb.y);
    const bool kb2 = (lb.w != lb.z);
    const bool kb3 = (lane < 63) && (nlabx != lb.w);
    const int s0 = 8 * lane;
    float best;
    best =             a0 + fmaxf(Bt[s0],     Bt[s0 + 1]);
    best = fmaxf(best, a1 + fmaxf(fmaxf(Bt[s0 + 1], Bt[s0 + 2]), kb0 ? Bt[s0 + 3] : NEGF));
    best = fmaxf(best, a2 + fmaxf(Bt[s0 + 2], Bt[s0 + 3]));
    best = fmaxf(best, a3 + fmaxf(fmaxf(Bt[s0 + 3], Bt[s0 + 4]), kb1 ? Bt[s0 + 5] : NEGF));
    best = fmaxf(best, a4 + fmaxf(Bt[s0 + 4], Bt[s0 + 5]));
    best = fmaxf(best, a5 + fmaxf(fmaxf(Bt[s0 + 5], Bt[s0 + 6]), kb2 ? Bt[s0 + 7] : NEGF));
    best = fmaxf(best, a6 + fmaxf(Bt[s0 + 6], Bt[s0 + 7]));
    best = fmaxf(best, a7 + fmaxf(fmaxf(Bt[s0 + 7], Bt[s0 + 8]), kb3 ? Bt[s0 + 9] : NEGF));
    best = fmaxf(best, a8 + Bt[512]);
#pragma unroll
    for (int off = 32; off; off >>= 1) best = fmaxf(best, __shfl_down(best, off));
    if (lane == 0) atomicAdd(acc, -best);
  }
}

// ---------------------------------------------------------------------------
// Kernel C: out = acc / sum(L_b)
// ---------------------------------------------------------------------------
__global__ __launch_bounds__(64) void finalize_kernel(
    const int* __restrict__ llen, const float* __restrict__ acc,
    float* __restrict__ out) {
  int Lsum = llen[threadIdx.x];   // B == 64 == blockDim
#pragma unroll
  for (int off = 32; off; off >>= 1) Lsum += __shfl_down(Lsum, off);
  if (threadIdx.x == 0) out[0] = acc[0] / (float)Lsum;
}

extern "C" void kernel_launch(void* const* d_in, const int* in_sizes, int n_in,
                              void* d_out, int out_size, void* d_ws, size_t ws_size,
                              hipStream_t stream) {
  const float* logits  = (const float*)d_in[0];   // [B,T,V] fp32
  const int*   targets = (const int*)d_in[1];     // [B,U] int32
  const int*   llen    = (const int*)d_in[2];     // [B]
  const int*   tlen    = (const int*)d_in[3];     // [B]
  float* out = (float*)d_out;

  // ws layout: [0,16) acc | [4096, 4096+512K) Ebs fp32 | [1MiB, 1MiB+64MiB) E bf16
  float*          acc = (float*)d_ws;
  float*          Ebs = (float*)((char*)d_ws + 4096);
  unsigned short* E   = (unsigned short*)((char*)d_ws + (1u << 20));

  hipMemsetAsync(acc, 0, 16, stream);
  gather_lse_kernel<<<Bb * 32, 256, 0, stream>>>(logits, targets, llen, acc, Ebs, E);
  viterbi_kernel<<<Bb, 128, 0, stream>>>(E, Ebs, targets, llen, tlen, acc);
  finalize_kernel<<<1, 64, 0, stream>>>(llen, acc, out);
}

// Round 7
// 279.280 us; speedup vs baseline: 1.2750x; 1.2750x over previous
//
#include <hip/hip_runtime.h>

#define NEGF -1e30f
typedef unsigned int uint32;

static constexpr int Bb = 64, Tt = 2048, Vv = 256, Uu = 256;
// S = 2*U+1 = 513 states; lane l owns states 8l..8l+7 (+512 on lane 63).
// Ebs layout (per batch, 2048 floats): Ebs[i] = blank[i+1] for i=0..2046,
// Ebs[2047] = blank[0].

__device__ __forceinline__ unsigned short f2bf(float f) {    // RNE, no NaN inputs
  uint32 u = __builtin_bit_cast(uint32, f);
  u += 0x7fffu + ((u >> 16) & 1u);
  return (unsigned short)(u >> 16);
}
__device__ __forceinline__ float bf2f_lo(uint32 p) { return __builtin_bit_cast(float, p << 16); }
__device__ __forceinline__ float bf2f_hi(uint32 p) { return __builtin_bit_cast(float, p & 0xffff0000u); }

// DPP cross-lane, gfx9-family wave-level shifts (1 VALU op, no LDS):
// wave_shr:1 (0x138): lane l <- lane l-1; lane 0 keeps `old` (bound_ctrl=0).
// wave_shl:1 (0x130): lane l <- lane l+1; lane 63 keeps `old`.
__device__ __forceinline__ float dpp_shr1(float old, float src) {
  return __builtin_bit_cast(float, __builtin_amdgcn_update_dpp(
      __builtin_bit_cast(int, old), __builtin_bit_cast(int, src), 0x138, 0xF, 0xF, false));
}
__device__ __forceinline__ float dpp_shl1(float old, float src) {
  return __builtin_bit_cast(float, __builtin_amdgcn_update_dpp(
      __builtin_bit_cast(int, old), __builtin_bit_cast(int, src), 0x130, 0xF, 0xF, false));
}

// ---------------------------------------------------------------------------
// Kernel A: one streaming pass over logits; 8 rows in flight per wave.
//   - acc[0] += sum of logsumexp over valid frames
//   - E[b][t][u] = bf16(logits[b][t][targets[b][u]]), t < L only
//   - Ebs shifted-blank array
// ---------------------------------------------------------------------------
__global__ __launch_bounds__(256) void gather_lse_kernel(
    const float* __restrict__ logits, const int* __restrict__ targets,
    const int* __restrict__ llen, float* __restrict__ acc,
    float* __restrict__ Ebs, unsigned short* __restrict__ E) {
  __shared__ __align__(16) float buf[4][8][Vv];   // 32 KB
  __shared__ float wpart[4];
  const int b = blockIdx.x >> 5;
  const int c = blockIdx.x & 31;
  const int w = threadIdx.x >> 6;
  const int lane = threadIdx.x & 63;
  const int L = llen[b];
  const int4 lb = reinterpret_cast<const int4*>(targets + (b << 8))[lane];
  const float* __restrict__ lgb = logits + (size_t)b * (Tt * Vv);
  float lse_local = 0.f;
#pragma unroll
  for (int k = 0; k < 2; ++k) {
    const int tbase = (c << 6) + (k << 5) + w;    // rows tbase + 4j, j=0..7
    if (tbase >= L) break;                        // wave-uniform
    float4 v[8];
#pragma unroll
    for (int j = 0; j < 8; ++j)
      v[j] = reinterpret_cast<const float4*>(lgb + (size_t)(tbase + 4 * j) * Vv)[lane];
    float s[8];
#pragma unroll
    for (int j = 0; j < 8; ++j)
      s[j] = __expf(v[j].x) + __expf(v[j].y) + __expf(v[j].z) + __expf(v[j].w);
#pragma unroll
    for (int off = 32; off; off >>= 1) {
#pragma unroll
      for (int j = 0; j < 8; ++j) s[j] += __shfl_down(s[j], off);
    }
#pragma unroll
    for (int j = 0; j < 8; ++j)
      reinterpret_cast<float4*>(&buf[w][j][0])[lane] = v[j];
#pragma unroll
    for (int j = 0; j < 8; ++j) {                 // intra-wave DS ordering
      const int t = tbase + 4 * j;
      const bool val = t < L;
      ushort4 o;
      o.x = f2bf(buf[w][j][lb.x]); o.y = f2bf(buf[w][j][lb.y]);
      o.z = f2bf(buf[w][j][lb.z]); o.w = f2bf(buf[w][j][lb.w]);
      if (val)
        reinterpret_cast<ushort4*>(E + ((size_t)((b << 11) + t)) * Vv)[lane] = o;
      if ((lane == 0) & val) {
        lse_local += __logf(s[j]);
        Ebs[(b << 11) + ((t == 0) ? 2047 : t - 1)] = v[j].x;   // row[0] = blank
      }
    }
  }
  if (lane == 0) wpart[w] = lse_local;
  __syncthreads();
  if (threadIdx.x == 0)
    atomicAdd(acc, wpart[0] + wpart[1] + wpart[2] + wpart[3]);
}

// ---------------------------------------------------------------------------
// Kernel B: bidirectional max-plus Viterbi, 2 waves per batch.
//   wave0: alpha forward t=0..M (em-inclusive), M=(L-2)>>1
//   wave1: beta backward t=L-1..M+1
//   merge: acc[0] -= max_s alpha[M][s] + max(beta[s], beta[s+1], skip? beta[s+2])
// R5 register-ring structure (PG=8 groups x 4 rows, sched_barrier-pinned) with
// the per-step cross-lane op done via DPP wave shifts instead of ds_bpermute
// (R5 measured 211 cyc/step: ~150 of it was exposed bpermute lgkm latency;
// R6's LDS-halo alternative regressed to 370 cyc/step on refresh round-trips).
// ---------------------------------------------------------------------------
#define PG 8
__global__ __launch_bounds__(128) void viterbi_kernel(
    const unsigned short* __restrict__ E, const float* __restrict__ Ebs,
    const int* __restrict__ targets, const int* __restrict__ llen,
    const int* __restrict__ tlen, float* __restrict__ acc) {
  __shared__ __align__(16) float LB[2048];   // blanks (shifted layout), 8 KB
  __shared__ float Bt[520];
  const int b = blockIdx.x;
  const int lane = threadIdx.x & 63;
  const int wv = threadIdx.x >> 6;
  const int L = llen[b];
  const int tl = tlen[b];
  const int M = (L - 2) >> 1;
  const int4 lb = reinterpret_cast<const int4*>(targets + (b << 8))[lane];
  const uint2* __restrict__ Erow = reinterpret_cast<const uint2*>(E) + ((size_t)(b << 11) << 6);
  const float* __restrict__ Ebb = Ebs + (b << 11);

  // cooperative blank preload: 2048 floats
  {
    const float4* src = reinterpret_cast<const float4*>(Ebb);
    float4* dst = reinterpret_cast<float4*>(LB);
    for (int i = threadIdx.x; i < 512; i += 128) dst[i] = src[i];
  }
  __syncthreads();

  float a0 = NEGF, a1 = NEGF, a2 = NEGF, a3 = NEGF, a4 = NEGF,
        a5 = NEGF, a6 = NEGF, a7 = NEGF, a8 = NEGF;

  if (wv == 0) {
    // ---------------- forward wave ----------------
    const int prevw = __shfl_up(lb.w, 1);
    const bool sk0 = (lane != 0) && (lb.x != prevw);
    const bool sk1 = (lb.y != lb.x);
    const bool sk2 = (lb.z != lb.y);
    const bool sk3 = (lb.w != lb.z);
    if (lane == 0) {
      a0 = LB[2047];                                            // blank[0]
      a1 = bf2f_lo((uint32)*reinterpret_cast<const unsigned short*>(E + ((size_t)(b << 11) << 8)));
    }
    uint2 pf[PG][4];
    float4 pb[PG];
    auto fetchf = [&](int slot, int k) {
      const int kk = (k > 511) ? 511 : k;
#pragma unroll
      for (int j = 0; j < 4; ++j) {
        int r = 1 + 4 * kk + j; r = (r > 2047) ? 2047 : r;
        pf[slot][j] = Erow[(size_t)(r << 6) + lane];
      }
      pb[slot] = reinterpret_cast<const float4*>(LB)[kk];       // blank[4kk+1..4kk+4]
    };
    auto stepf = [&](uint2 em, float eb) {
      const float e0 = bf2f_lo(em.x), e1 = bf2f_hi(em.x);
      const float e2 = bf2f_lo(em.y), e3 = bf2f_hi(em.y);
      const float am1 = dpp_shr1(NEGF, a7);                     // lane0 -> NEGF
      const float x0 = fmaxf(a0, am1) + eb;
      const float x1 = fmaxf(fmaxf(a1, a0), sk0 ? am1 : NEGF) + e0;
      const float x2 = fmaxf(a2, a1) + eb;
      const float x3 = fmaxf(fmaxf(a3, a2), sk1 ? a1 : NEGF) + e1;
      const float x4 = fmaxf(a4, a3) + eb;
      const float x5 = fmaxf(fmaxf(a5, a4), sk2 ? a3 : NEGF) + e2;
      const float x6 = fmaxf(a6, a5) + eb;
      const float x7 = fmaxf(fmaxf(a7, a6), sk3 ? a5 : NEGF) + e3;
      const float x8 = fmaxf(a8, a7) + eb;
      a0 = x0; a1 = x1; a2 = x2; a3 = x3; a4 = x4; a5 = x5; a6 = x6; a7 = x7; a8 = x8;
    };
    const int n = M, Gf = n >> 2, remf = n & 3;
#pragma unroll
    for (int s = 0; s < PG; ++s) fetchf(s, s);
    __builtin_amdgcn_sched_barrier(0);
    int g = 0;
    while (g + PG <= Gf) {
#pragma unroll
      for (int s = 0; s < PG; ++s) {
#pragma unroll
        for (int j = 0; j < 4; ++j) stepf(pf[s][j], (&pb[s].x)[j]);
        fetchf(s, g + s + PG);
        __builtin_amdgcn_sched_barrier(0);
      }
      g += PG;
    }
    const int left = Gf - g;   // 0..PG-1
#pragma unroll
    for (int s = 0; s < PG; ++s) {
      if (s < left) {
#pragma unroll
        for (int j = 0; j < 4; ++j) stepf(pf[s][j], (&pb[s].x)[j]);
      }
    }
#pragma unroll
    for (int s = 0; s < PG; ++s) {
      if (s == left) {
#pragma unroll
        for (int j = 0; j < 4; ++j)
          if (j < remf) stepf(pf[s][j], (&pb[s].x)[j]);
      }
    }
  } else {
    // ---------------- backward wave ----------------
    const int nlabx = __shfl_down(lb.x, 1);
    const bool kb0 = (lb.y != lb.x);
    const bool kb1 = (lb.z != lb.y);
    const bool kb2 = (lb.w != lb.z);
    const bool kb3 = (lane < 63) && (nlabx != lb.w);
    {
      const uint2 er = Erow[(size_t)((L - 1) << 6) + lane];
      const float e0 = bf2f_lo(er.x), e1 = bf2f_hi(er.x);
      const float e2 = bf2f_lo(er.y), e3 = bf2f_hi(er.y);
      const float blankL = LB[L - 2];                           // blank[L-1]
      const int s0 = 8 * lane, tb = 2 * tl, tm = 2 * tl - 1;
      a0 = (s0     == tb) ? blankL : NEGF;
      a1 = (s0 + 1 == tm) ? e0     : NEGF;
      a2 = (s0 + 2 == tb) ? blankL : NEGF;
      a3 = (s0 + 3 == tm) ? e1     : NEGF;
      a4 = (s0 + 4 == tb) ? blankL : NEGF;
      a5 = (s0 + 5 == tm) ? e2     : NEGF;
      a6 = (s0 + 6 == tb) ? blankL : NEGF;
      a7 = (s0 + 7 == tm) ? e3     : NEGF;
      a8 = ((lane == 63) && (tb == 512)) ? blankL : NEGF;
    }
    uint2 qf[PG][4];
    float qb[PG][4];
    auto fetchb = [&](int slot, int k) {
#pragma unroll
      for (int j = 0; j < 4; ++j) {
        int r = L - 2 - 4 * k - j; r = (r < 1) ? 1 : r;
        qf[slot][j] = Erow[(size_t)(r << 6) + lane];
        qb[slot][j] = LB[r - 1];                                // blank[r]
      }
    };
    auto stepb = [&](uint2 em, float eb) {
      const float e0 = bf2f_lo(em.x), e1 = bf2f_hi(em.x);
      const float e2 = bf2f_lo(em.y), e3 = bf2f_hi(em.y);
      const float bn0 = dpp_shl1(a8, a0);     // lane l: a0[l+1]; lane63: own a8
      const float bn1 = dpp_shl1(NEGF, a1);   // lane l: a1[l+1]; lane63: NEGF
      const float y0 = fmaxf(a0, a1) + eb;
      const float y1 = fmaxf(fmaxf(a1, a2), kb0 ? a3 : NEGF) + e0;
      const float y2 = fmaxf(a2, a3) + eb;
      const float y3 = fmaxf(fmaxf(a3, a4), kb1 ? a5 : NEGF) + e1;
      const float y4 = fmaxf(a4, a5) + eb;
      const float y5 = fmaxf(fmaxf(a5, a6), kb2 ? a7 : NEGF) + e2;
      const float y6 = fmaxf(a6, a7) + eb;
      const float y7 = fmaxf(fmaxf(a7, bn0), kb3 ? bn1 : NEGF) + e3;
      const float y8 = a8 + eb;
      a0 = y0; a1 = y1; a2 = y2; a3 = y3; a4 = y4; a5 = y5; a6 = y6; a7 = y7; a8 = y8;
    };
    const int n = L - 2 - M, Gb = n >> 2, remb = n & 3;
#pragma unroll
    for (int s = 0; s < PG; ++s) fetchb(s, s);
    __builtin_amdgcn_sched_barrier(0);
    int g = 0;
    while (g + PG <= Gb) {
#pragma unroll
      for (int s = 0; s < PG; ++s) {
#pragma unroll
        for (int j = 0; j < 4; ++j) stepb(qf[s][j], qb[s][j]);
        fetchb(s, g + s + PG);
        __builtin_amdgcn_sched_barrier(0);
      }
      g += PG;
    }
    const int left = Gb - g;
#pragma unroll
    for (int s = 0; s < PG; ++s) {
      if (s < left) {
#pragma unroll
        for (int j = 0; j < 4; ++j) stepb(qf[s][j], qb[s][j]);
      }
    }
#pragma unroll
    for (int s = 0; s < PG; ++s) {
      if (s == left) {
#pragma unroll
        for (int j = 0; j < 4; ++j)
          if (j < remb) stepb(qf[s][j], qb[s][j]);
      }
    }
    // dump beta[M+1] to LDS (+NEG padding)
    Bt[8 * lane + 0] = a0; Bt[8 * lane + 1] = a1;
    Bt[8 * lane + 2] = a2; Bt[8 * lane + 3] = a3;
    Bt[8 * lane + 4] = a4; Bt[8 * lane + 5] = a5;
    Bt[8 * lane + 6] = a6; Bt[8 * lane + 7] = a7;
    if (lane == 63) Bt[512] = a8;
    if (lane == 0) { Bt[513] = NEGF; Bt[514] = NEGF; }
  }
  __syncthreads();
  if (wv == 0) {
    const int nlabx = __shfl_down(lb.x, 1);
    const bool kb0 = (lb.y != lb.x);
    const bool kb1 = (lb.z != lb.y);
    const bool kb2 = (lb.w != lb.z);
    const bool kb3 = (lane < 63) && (nlabx != lb.w);
    const int s0 = 8 * lane;
    float best;
    best =             a0 + fmaxf(Bt[s0],     Bt[s0 + 1]);
    best = fmaxf(best, a1 + fmaxf(fmaxf(Bt[s0 + 1], Bt[s0 + 2]), kb0 ? Bt[s0 + 3] : NEGF));
    best = fmaxf(best, a2 + fmaxf(Bt[s0 + 2], Bt[s0 + 3]));
    best = fmaxf(best, a3 + fmaxf(fmaxf(Bt[s0 + 3], Bt[s0 + 4]), kb1 ? Bt[s0 + 5] : NEGF));
    best = fmaxf(best, a4 + fmaxf(Bt[s0 + 4], Bt[s0 + 5]));
    best = fmaxf(best, a5 + fmaxf(fmaxf(Bt[s0 + 5], Bt[s0 + 6]), kb2 ? Bt[s0 + 7] : NEGF));
    best = fmaxf(best, a6 + fmaxf(Bt[s0 + 6], Bt[s0 + 7]));
    best = fmaxf(best, a7 + fmaxf(fmaxf(Bt[s0 + 7], Bt[s0 + 8]), kb3 ? Bt[s0 + 9] : NEGF));
    best = fmaxf(best, a8 + Bt[512]);
#pragma unroll
    for (int off = 32; off; off >>= 1) best = fmaxf(best, __shfl_down(best, off));
    if (lane == 0) atomicAdd(acc, -best);
  }
}

// ---------------------------------------------------------------------------
// Kernel C: out = acc / sum(L_b)
// ---------------------------------------------------------------------------
__global__ __launch_bounds__(64) void finalize_kernel(
    const int* __restrict__ llen, const float* __restrict__ acc,
    float* __restrict__ out) {
  int Lsum = llen[threadIdx.x];   // B == 64 == blockDim
#pragma unroll
  for (int off = 32; off; off >>= 1) Lsum += __shfl_down(Lsum, off);
  if (threadIdx.x == 0) out[0] = acc[0] / (float)Lsum;
}

extern "C" void kernel_launch(void* const* d_in, const int* in_sizes, int n_in,
                              void* d_out, int out_size, void* d_ws, size_t ws_size,
                              hipStream_t stream) {
  const float* logits  = (const float*)d_in[0];   // [B,T,V] fp32
  const int*   targets = (const int*)d_in[1];     // [B,U] int32
  const int*   llen    = (const int*)d_in[2];     // [B]
  const int*   tlen    = (const int*)d_in[3];     // [B]
  float* out = (float*)d_out;

  // ws layout: [0,16) acc | [4096, 4096+512K) Ebs fp32 | [1MiB, 1MiB+64MiB) E bf16
  float*          acc = (float*)d_ws;
  float*          Ebs = (float*)((char*)d_ws + 4096);
  unsigned short* E   = (unsigned short*)((char*)d_ws + (1u << 20));

  hipMemsetAsync(acc, 0, 16, stream);
  gather_lse_kernel<<<Bb * 32, 256, 0, stream>>>(logits, targets, llen, acc, Ebs, E);
  viterbi_kernel<<<Bb, 128, 0, stream>>>(E, Ebs, targets, llen, tlen, acc);
  finalize_kernel<<<1, 64, 0, stream>>>(llen, acc, out);
}